// Round 2
// baseline (29.227 us; speedup 1.0000x reference)
//
#include <hip/hip_runtime.h>
#include <math.h>

#define BATCH 8
#define LEN   2048
#define FEAT  8
#define ROWS  32                    // pred rows per block
#define JSPL  8                     // lanes cooperating per row (j-split)
#define THREADS (ROWS * JSPL)       // 256
#define CHUNK 1024                  // target rows staged per phase (36 KB LDS)
#define NPHASE (LEN / CHUNK)
#define NBLK  (BATCH * (LEN / ROWS))  // 512 blocks

// Per block: 32 pred rows of one batch. Stage target batch into LDS in two
// 1024-row phases, pre-doubled (2*t) with -||t||^2 alongside, so the inner
// loop is: x = (-||p||^2 + -||t||^2) then 8 FMAs -> x = -dist, s += expf(x).
// No max-tracking: x <= 0 and min dist over 2048 normal candidates in 8-D is
// small, so sum(exp) is always well inside f32 range.
template <bool ATOMIC>
__global__ __launch_bounds__(THREADS) void dtw_rows(
    const float* __restrict__ pred, const float* __restrict__ target,
    float* __restrict__ partial_or_out)
{
    __shared__ float4 s_t[CHUNK * 2];   // doubled target rows, 32 KB
    __shared__ float  s_mt2[CHUNK];     // -||t||^2, 4 KB
    __shared__ float  s_wsum[THREADS / 64];

    const int tid = threadIdx.x;
    const int b   = blockIdx.x / (LEN / ROWS);
    const int rb  = blockIdx.x % (LEN / ROWS);
    const int r   = tid >> 3;   // row within block
    const int c   = tid & 7;    // j-lane within row group
    const int i   = rb * ROWS + r;

    const float4* p4 = (const float4*)(pred + ((size_t)b * LEN + i) * FEAT);
    const float4 pa = p4[0];
    const float4 pb = p4[1];
    const float mp2 = -(pa.x*pa.x + pa.y*pa.y + pa.z*pa.z + pa.w*pa.w
                      + pb.x*pb.x + pb.y*pb.y + pb.z*pb.z + pb.w*pb.w);

    const float4* t4 = (const float4*)(target + (size_t)b * LEN * FEAT);

    float s = 0.f;
    for (int ph = 0; ph < NPHASE; ++ph) {
        const int j0 = ph * CHUNK;
        // ---- stage: doubled target + (-t2) ----
        for (int jj = tid; jj < CHUNK; jj += THREADS) {
            float4 ta = t4[(size_t)(j0 + jj) * 2];
            float4 tb = t4[(size_t)(j0 + jj) * 2 + 1];
            float t2 = ta.x*ta.x + ta.y*ta.y + ta.z*ta.z + ta.w*ta.w
                     + tb.x*tb.x + tb.y*tb.y + tb.z*tb.z + tb.w*tb.w;
            s_t[jj * 2]     = make_float4(ta.x + ta.x, ta.y + ta.y,
                                          ta.z + ta.z, ta.w + ta.w);
            s_t[jj * 2 + 1] = make_float4(tb.x + tb.x, tb.y + tb.y,
                                          tb.z + tb.z, tb.w + tb.w);
            s_mt2[jj] = -t2;
        }
        __syncthreads();
        // ---- inner loop over this phase's target rows ----
        for (int jj = c; jj < CHUNK; jj += JSPL) {
            float4 ta = s_t[jj * 2];
            float4 tb = s_t[jj * 2 + 1];
            float x = mp2 + s_mt2[jj];
            x = fmaf(ta.x, pa.x, x);
            x = fmaf(ta.y, pa.y, x);
            x = fmaf(ta.z, pa.z, x);
            x = fmaf(ta.w, pa.w, x);
            x = fmaf(tb.x, pb.x, x);
            x = fmaf(tb.y, pb.y, x);
            x = fmaf(tb.z, pb.z, x);
            x = fmaf(tb.w, pb.w, x);   // x = -dist(i, j0+jj)
            s += __expf(x);
        }
        __syncthreads();
    }

    // ---- merge the 8 j-lanes of each row (butterfly: all lanes get sum) ----
    s += __shfl_xor(s, 1);
    s += __shfl_xor(s, 2);
    s += __shfl_xor(s, 4);
    float v = -__logf(s);          // soft-min for this row (gamma = 1)
    // ---- sum rows within the wave ----------------------------------------
    // lanes = 8 rows (bits 3-5) x 8 c-lanes (bits 0-2); butterfly over bits
    // 3-5 combines the 8 DISTINCT rows at fixed c -> each lane = sum of 8
    // rows, NO replication factor (the c-groups just redundantly compute the
    // same sum). Do NOT divide by 8 here (round-1 bug: output was ref/8).
    v += __shfl_xor(v, 8);
    v += __shfl_xor(v, 16);
    v += __shfl_xor(v, 32);
    const int wave = tid >> 6;
    if ((tid & 63) == 0) s_wsum[wave] = v;
    __syncthreads();
    if (tid == 0) {
        float tot = 0.f;
        #pragma unroll
        for (int w = 0; w < THREADS / 64; ++w) tot += s_wsum[w];
        if (ATOMIC) {
            atomicAdd(partial_or_out, tot * (1.0f / (BATCH * LEN)));
        } else {
            partial_or_out[blockIdx.x] = tot;
        }
    }
}

__global__ __launch_bounds__(256) void dtw_reduce(
    const float* __restrict__ partial, float* __restrict__ out)
{
    __shared__ float s_w[4];
    const int tid = threadIdx.x;
    float v = partial[tid] + partial[tid + 256];   // NBLK = 512
    v += __shfl_xor(v, 1);
    v += __shfl_xor(v, 2);
    v += __shfl_xor(v, 4);
    v += __shfl_xor(v, 8);
    v += __shfl_xor(v, 16);
    v += __shfl_xor(v, 32);
    if ((tid & 63) == 0) s_w[tid >> 6] = v;
    __syncthreads();
    if (tid == 0)
        out[0] = (s_w[0] + s_w[1] + s_w[2] + s_w[3]) * (1.0f / (BATCH * LEN));
}

extern "C" void kernel_launch(void* const* d_in, const int* in_sizes, int n_in,
                              void* d_out, int out_size, void* d_ws, size_t ws_size,
                              hipStream_t stream) {
    const float* pred   = (const float*)d_in[0];
    const float* target = (const float*)d_in[1];
    float* out = (float*)d_out;

    if (ws_size >= NBLK * sizeof(float)) {
        float* partial = (float*)d_ws;
        dtw_rows<false><<<NBLK, THREADS, 0, stream>>>(pred, target, partial);
        dtw_reduce<<<1, 256, 0, stream>>>(partial, out);
    } else {
        // fallback: zero the output then atomically accumulate
        hipMemsetAsync(d_out, 0, sizeof(float), stream);
        dtw_rows<true><<<NBLK, THREADS, 0, stream>>>(pred, target, out);
    }
}

// Round 3
// 24.175 us; speedup vs baseline: 1.2090x; 1.2090x over previous
//
#include <hip/hip_runtime.h>
#include <math.h>

#define BATCH 8
#define LEN   2048
#define FEAT  8
#define IR    8                     // pred rows register-tiled per lane
#define WAVES 4
#define THREADS (WAVES * 64)        // 256
#define ROWS  (WAVES * IR)          // 32 pred rows per block
#define CHUNK 1024                  // target rows staged per phase (36 KB LDS)
#define NPHASE (LEN / CHUNK)
#define NBLK  (BATCH * (LEN / ROWS))  // 512 blocks
#define LOG2E 1.4426950408889634f
#define LN2   0.6931471805599453f

typedef float v2f __attribute__((ext_vector_type(2)));

__device__ __forceinline__ v2f pk_mul(v2f a, v2f b) {
    v2f d; asm("v_pk_mul_f32 %0, %1, %2" : "=v"(d) : "v"(a), "v"(b)); return d;
}
__device__ __forceinline__ v2f pk_fma(v2f a, v2f b, v2f c) {
    v2f d; asm("v_pk_fma_f32 %0, %1, %2, %3" : "=v"(d) : "v"(a), "v"(b), "v"(c)); return d;
}

#if __has_builtin(__builtin_amdgcn_exp2f)
#define EXP2F(x) __builtin_amdgcn_exp2f(x)
#else
#define EXP2F(x) exp2f(x)
#endif
#if __has_builtin(__builtin_amdgcn_logf)
#define LOG2FH(x) __builtin_amdgcn_logf(x)   // hardware log2
#else
#define LOG2FH(x) log2f(x)
#endif

// Per block: 32 pred rows (4 waves x 8 rows-in-registers). Target batch staged
// in two 1024-row LDS phases, pre-scaled: t_s = (2*log2e)*t, mt2 = -log2e*||t||^2,
// mp2 = -log2e*||p||^2, so x = mp2 + mt2 + p.t_s = log2e*(-dist) and
// exp2(x) = exp(-dist). One LDS t-read serves 8 pred rows (IR register tiling).
// LDS granule index swizzled g = 2j + ((j>>2)&1): 8 consecutive lanes' b128
// reads start at banks {0,8,16,24,4,12,20,28} -> conflict-free (both halves).
template <bool ATOMIC>
__global__ __launch_bounds__(THREADS) void dtw_rows(
    const float* __restrict__ pred, const float* __restrict__ target,
    float* __restrict__ partial_or_out)
{
    __shared__ float4 s_t[CHUNK * 2];   // swizzled scaled target rows, 32 KB
    __shared__ float  s_mt2[CHUNK];     // -log2e*||t||^2, 4 KB
    __shared__ float  s_wsum[WAVES];

    const int tid = threadIdx.x;
    const int b   = blockIdx.x / (LEN / ROWS);
    const int rb  = blockIdx.x % (LEN / ROWS);
    const int w   = tid >> 6;           // wave = row-group
    const int ln  = tid & 63;           // j-lane within wave
    const int i0  = rb * ROWS + w * IR;

    // ---- load this wave's 8 pred rows into registers (broadcast loads) ----
    const float4* p4 = (const float4*)(pred + ((size_t)b * LEN + i0) * FEAT);
    v2f  pr[IR][4];
    float mp2[IR];
    #pragma unroll
    for (int r = 0; r < IR; ++r) {
        float4 a = p4[r * 2];
        float4 c = p4[r * 2 + 1];
        pr[r][0] = (v2f){a.x, a.y};
        pr[r][1] = (v2f){a.z, a.w};
        pr[r][2] = (v2f){c.x, c.y};
        pr[r][3] = (v2f){c.z, c.w};
        mp2[r] = -LOG2E * (a.x*a.x + a.y*a.y + a.z*a.z + a.w*a.w
                         + c.x*c.x + c.y*c.y + c.z*c.z + c.w*c.w);
    }

    const float4* t4 = (const float4*)(target + (size_t)b * LEN * FEAT);
    float acc[IR];
    #pragma unroll
    for (int r = 0; r < IR; ++r) acc[r] = 0.f;

    for (int ph = 0; ph < NPHASE; ++ph) {
        const int j0 = ph * CHUNK;
        if (ph) __syncthreads();   // prior phase's reads done before overwrite
        // ---- stage: scaled target + (-log2e*t2), swizzled ----
        for (int jj = tid; jj < CHUNK; jj += THREADS) {
            float4 ta = t4[(size_t)(j0 + jj) * 2];
            float4 tb = t4[(size_t)(j0 + jj) * 2 + 1];
            float t2 = ta.x*ta.x + ta.y*ta.y + ta.z*ta.z + ta.w*ta.w
                     + tb.x*tb.x + tb.y*tb.y + tb.z*tb.z + tb.w*tb.w;
            const float s2 = 2.f * LOG2E;
            int g = 2 * jj + ((jj >> 2) & 1);
            s_t[g]     = make_float4(ta.x*s2, ta.y*s2, ta.z*s2, ta.w*s2);
            s_t[g ^ 1] = make_float4(tb.x*s2, tb.y*s2, tb.z*s2, tb.w*s2);
            s_mt2[jj] = -LOG2E * t2;
        }
        __syncthreads();
        // ---- inner: each lane sweeps 16 j's per phase x 8 rows ----
        #pragma unroll 2
        for (int k = 0; k < CHUNK / 64; ++k) {
            const int jj = k * 64 + ln;
            const int g  = 2 * jj + ((jj >> 2) & 1);
            float4 ta = s_t[g];
            float4 tb = s_t[g ^ 1];
            float mt2s = s_mt2[jj];
            v2f t01 = (v2f){ta.x, ta.y};
            v2f t23 = (v2f){ta.z, ta.w};
            v2f t45 = (v2f){tb.x, tb.y};
            v2f t67 = (v2f){tb.z, tb.w};
            #pragma unroll
            for (int r = 0; r < IR; ++r) {
                v2f a2 = pk_mul(t01, pr[r][0]);
                a2 = pk_fma(t23, pr[r][1], a2);
                a2 = pk_fma(t45, pr[r][2], a2);
                a2 = pk_fma(t67, pr[r][3], a2);
                float x = (a2.x + a2.y) + (mp2[r] + mt2s);
                acc[r] += EXP2F(x);          // = exp(-dist(i0+?, jj))
            }
        }
    }

    // ---- per-row totals across the wave's 64 j-lanes, then soft-min ----
    float vt = 0.f;
    #pragma unroll
    for (int r = 0; r < IR; ++r) {
        float s = acc[r];
        s += __shfl_xor(s, 1);
        s += __shfl_xor(s, 2);
        s += __shfl_xor(s, 4);
        s += __shfl_xor(s, 8);
        s += __shfl_xor(s, 16);
        s += __shfl_xor(s, 32);
        vt += LOG2FH(s);                 // log2(sum exp(-d))
    }
    vt *= -LN2;                          // -gamma * ln(sum) summed over 8 rows
    if (ln == 0) s_wsum[w] = vt;
    __syncthreads();
    if (tid == 0) {
        float tot = s_wsum[0] + s_wsum[1] + s_wsum[2] + s_wsum[3];
        if (ATOMIC) {
            atomicAdd(partial_or_out, tot * (1.0f / (BATCH * LEN)));
        } else {
            partial_or_out[blockIdx.x] = tot;
        }
    }
}

__global__ __launch_bounds__(256) void dtw_reduce(
    const float* __restrict__ partial, float* __restrict__ out)
{
    __shared__ float s_w[4];
    const int tid = threadIdx.x;
    float v = partial[tid] + partial[tid + 256];   // NBLK = 512
    v += __shfl_xor(v, 1);
    v += __shfl_xor(v, 2);
    v += __shfl_xor(v, 4);
    v += __shfl_xor(v, 8);
    v += __shfl_xor(v, 16);
    v += __shfl_xor(v, 32);
    if ((tid & 63) == 0) s_w[tid >> 6] = v;
    __syncthreads();
    if (tid == 0)
        out[0] = (s_w[0] + s_w[1] + s_w[2] + s_w[3]) * (1.0f / (BATCH * LEN));
}

extern "C" void kernel_launch(void* const* d_in, const int* in_sizes, int n_in,
                              void* d_out, int out_size, void* d_ws, size_t ws_size,
                              hipStream_t stream) {
    const float* pred   = (const float*)d_in[0];
    const float* target = (const float*)d_in[1];
    float* out = (float*)d_out;

    if (ws_size >= NBLK * sizeof(float)) {
        float* partial = (float*)d_ws;
        dtw_rows<false><<<NBLK, THREADS, 0, stream>>>(pred, target, partial);
        dtw_reduce<<<1, 256, 0, stream>>>(partial, out);
    } else {
        hipMemsetAsync(d_out, 0, sizeof(float), stream);
        dtw_rows<true><<<NBLK, THREADS, 0, stream>>>(pred, target, out);
    }
}

// Round 4
// 23.501 us; speedup vs baseline: 1.2437x; 1.0287x over previous
//
#include <hip/hip_runtime.h>
#include <math.h>

#define BATCH 8
#define LEN   2048
#define FEAT  8
#define IR    4                     // pred rows register-tiled per lane
#define WAVES 4
#define THREADS (WAVES * 64)        // 256
#define ROWS  (WAVES * IR)          // 16 pred rows per block
#define CHUNK 1024                  // target rows staged per phase (36 KB LDS)
#define NPHASE (LEN / CHUNK)
#define KSTEPS (CHUNK / 64)         // 16 j-iterations per lane per phase
#define NBLK  (BATCH * (LEN / ROWS))  // 1024 blocks = 4/CU
#define LOG2E 1.4426950408889634f
#define LN2   0.6931471805599453f

typedef float v2f __attribute__((ext_vector_type(2)));

__device__ __forceinline__ v2f pk_mul(v2f a, v2f b) {
    v2f d; asm("v_pk_mul_f32 %0, %1, %2" : "=v"(d) : "v"(a), "v"(b)); return d;
}
__device__ __forceinline__ v2f pk_fma(v2f a, v2f b, v2f c) {
    v2f d; asm("v_pk_fma_f32 %0, %1, %2, %3" : "=v"(d) : "v"(a), "v"(b), "v"(c)); return d;
}

#if __has_builtin(__builtin_amdgcn_exp2f)
#define EXP2F(x) __builtin_amdgcn_exp2f(x)
#else
#define EXP2F(x) exp2f(x)
#endif
#if __has_builtin(__builtin_amdgcn_logf)
#define LOG2FH(x) __builtin_amdgcn_logf(x)   // hardware log2
#else
#define LOG2FH(x) log2f(x)
#endif

// Per block: 16 pred rows (4 waves x 4 rows-in-registers), all 2048 targets in
// two 1024-row LDS phases. Scaling folded into the per-block pred load:
//   pr = (2*log2e)*p, mp2 = -log2e*||p||^2, s_mt2 = -log2e*||t||^2, s_t = t.
//   x = pr.t + mp2 + mt2 = -log2e*dist;  exp2(x) = exp(-dist).
// LDS granule swizzle g = 2j + ((j>>2)&1): 8 consecutive lanes' b128 reads
// start at banks {0,8,16,24,4,12,20,28} -> conflict-free.
// 1024 blocks = 4 blocks/CU (LDS 4x36.9KB), 4 waves/SIMD for latency hiding;
// inner loop software-prefetches j(k+1)'s LDS data during j(k)'s compute.
template <bool ATOMIC>
__global__ __launch_bounds__(THREADS, 4) void dtw_rows(
    const float* __restrict__ pred, const float* __restrict__ target,
    float* __restrict__ partial_or_out)
{
    __shared__ float4 s_t[CHUNK * 2];   // swizzled target rows, 32 KB
    __shared__ float  s_mt2[CHUNK];     // -log2e*||t||^2, 4 KB
    __shared__ float  s_wsum[WAVES];

    const int tid = threadIdx.x;
    const int b   = blockIdx.x / (LEN / ROWS);
    const int rb  = blockIdx.x % (LEN / ROWS);
    const int w   = tid >> 6;           // wave = row-group
    const int ln  = tid & 63;           // j-lane within wave
    const int i0  = rb * ROWS + w * IR;

    // ---- this wave's 4 pred rows -> registers, pre-scaled by 2*log2e ----
    const float4* p4 = (const float4*)(pred + ((size_t)b * LEN + i0) * FEAT);
    v2f  pr[IR][4];
    float mp2[IR];
    #pragma unroll
    for (int r = 0; r < IR; ++r) {
        float4 a = p4[r * 2];
        float4 c = p4[r * 2 + 1];
        const float s2 = 2.f * LOG2E;
        pr[r][0] = (v2f){a.x * s2, a.y * s2};
        pr[r][1] = (v2f){a.z * s2, a.w * s2};
        pr[r][2] = (v2f){c.x * s2, c.y * s2};
        pr[r][3] = (v2f){c.z * s2, c.w * s2};
        mp2[r] = -LOG2E * (a.x*a.x + a.y*a.y + a.z*a.z + a.w*a.w
                         + c.x*c.x + c.y*c.y + c.z*c.z + c.w*c.w);
    }

    const float4* t4 = (const float4*)(target + (size_t)b * LEN * FEAT);
    float acc[IR];
    #pragma unroll
    for (int r = 0; r < IR; ++r) acc[r] = 0.f;

    for (int ph = 0; ph < NPHASE; ++ph) {
        const int j0 = ph * CHUNK;
        if (ph) __syncthreads();   // prior phase's reads done before overwrite
        // ---- stage: raw target rows (swizzled) + -log2e*||t||^2 ----
        for (int jj = tid; jj < CHUNK; jj += THREADS) {   // 4 iters
            float4 ta = t4[(size_t)(j0 + jj) * 2];
            float4 tb = t4[(size_t)(j0 + jj) * 2 + 1];
            float t2 = ta.x*ta.x + ta.y*ta.y + ta.z*ta.z + ta.w*ta.w
                     + tb.x*tb.x + tb.y*tb.y + tb.z*tb.z + tb.w*tb.w;
            int g = 2 * jj + ((jj >> 2) & 1);
            s_t[g]     = ta;
            s_t[g ^ 1] = tb;
            s_mt2[jj] = -LOG2E * t2;
        }
        __syncthreads();
        // ---- inner: prefetch-pipelined sweep, 16 j's per lane ----
        {
            int gcur = 2 * ln + ((ln >> 2) & 1);
            float4 ta = s_t[gcur];
            float4 tb = s_t[gcur ^ 1];
            float mt2 = s_mt2[ln];
            #pragma unroll
            for (int k = 0; k < KSTEPS; ++k) {
                float4 na, nb; float nmt = 0.f;
                if (k + 1 < KSTEPS) {
                    const int jn = (k + 1) * 64 + ln;
                    const int gn = 2 * jn + ((jn >> 2) & 1);
                    na  = s_t[gn];
                    nb  = s_t[gn ^ 1];
                    nmt = s_mt2[jn];
                }
                v2f t01 = (v2f){ta.x, ta.y};
                v2f t23 = (v2f){ta.z, ta.w};
                v2f t45 = (v2f){tb.x, tb.y};
                v2f t67 = (v2f){tb.z, tb.w};
                #pragma unroll
                for (int r = 0; r < IR; ++r) {
                    v2f a2 = pk_mul(t01, pr[r][0]);
                    a2 = pk_fma(t23, pr[r][1], a2);
                    a2 = pk_fma(t45, pr[r][2], a2);
                    a2 = pk_fma(t67, pr[r][3], a2);
                    float x = (a2.x + a2.y) + (mp2[r] + mt2);
                    acc[r] += EXP2F(x);          // = exp(-dist)
                }
                if (k + 1 < KSTEPS) { ta = na; tb = nb; mt2 = nmt; }
            }
        }
    }

    // ---- per-row totals across the wave's 64 j-lanes, then soft-min ----
    float vt = 0.f;
    #pragma unroll
    for (int r = 0; r < IR; ++r) {
        float s = acc[r];
        s += __shfl_xor(s, 1);
        s += __shfl_xor(s, 2);
        s += __shfl_xor(s, 4);
        s += __shfl_xor(s, 8);
        s += __shfl_xor(s, 16);
        s += __shfl_xor(s, 32);
        vt += LOG2FH(s);                 // log2(sum exp(-d))
    }
    vt *= -LN2;                          // sum over this wave's 4 rows
    if (ln == 0) s_wsum[w] = vt;
    __syncthreads();
    if (tid == 0) {
        float tot = s_wsum[0] + s_wsum[1] + s_wsum[2] + s_wsum[3];
        if (ATOMIC) {
            atomicAdd(partial_or_out, tot * (1.0f / (BATCH * LEN)));
        } else {
            partial_or_out[blockIdx.x] = tot;
        }
    }
}

__global__ __launch_bounds__(256) void dtw_reduce(
    const float* __restrict__ partial, float* __restrict__ out)
{
    __shared__ float s_w[4];
    const int tid = threadIdx.x;
    float v = partial[tid] + partial[tid + 256]
            + partial[tid + 512] + partial[tid + 768];   // NBLK = 1024
    v += __shfl_xor(v, 1);
    v += __shfl_xor(v, 2);
    v += __shfl_xor(v, 4);
    v += __shfl_xor(v, 8);
    v += __shfl_xor(v, 16);
    v += __shfl_xor(v, 32);
    if ((tid & 63) == 0) s_w[tid >> 6] = v;
    __syncthreads();
    if (tid == 0)
        out[0] = (s_w[0] + s_w[1] + s_w[2] + s_w[3]) * (1.0f / (BATCH * LEN));
}

extern "C" void kernel_launch(void* const* d_in, const int* in_sizes, int n_in,
                              void* d_out, int out_size, void* d_ws, size_t ws_size,
                              hipStream_t stream) {
    const float* pred   = (const float*)d_in[0];
    const float* target = (const float*)d_in[1];
    float* out = (float*)d_out;

    if (ws_size >= NBLK * sizeof(float)) {
        float* partial = (float*)d_ws;
        dtw_rows<false><<<NBLK, THREADS, 0, stream>>>(pred, target, partial);
        dtw_reduce<<<1, 256, 0, stream>>>(partial, out);
    } else {
        hipMemsetAsync(d_out, 0, sizeof(float), stream);
        dtw_rows<true><<<NBLK, THREADS, 0, stream>>>(pred, target, out);
    }
}